// Round 22
// baseline (81.076 us; speedup 1.0000x reference)
//
#include <hip/hip_runtime.h>
#include <math.h>

#define NWIN 7
#define P2 49
#define NB 8
#define NP 392          // NB*P2
#define CDIM 128
#define HH 56
#define PROJC 384
#define HEADS 8
#define HD 16
#define TOPK 4
#define SCALE 0.08838834764831843f   // 128^-0.5
#define QSCALE 0.12751743050337065f  // SCALE * log2(e); v_exp_f32 computes 2^x

typedef __attribute__((ext_vector_type(4))) float f4;
typedef __attribute__((ext_vector_type(4))) short v4s;
typedef unsigned long long u64;

// gfx950 v_mfma_f32_16x16x16_bf16; fragment maps HW-validated (rounds 5-21):
//   A[row][k]: row=lane&15, k=4*(lane>>4)+i ; B[k][col]: col=lane&15, same k
//   D[row][col]: col=lane&15, row=4*(lane>>4)+reg
#define MFMA16(a,b,c) __builtin_amdgcn_mfma_f32_16x16x16bf16_1k(a,b,c,0,0,0)

__device__ inline unsigned short f2bf(float x) {
    union { float f; unsigned u; } v; v.f = x;
    const unsigned r = v.u + 0x7FFFu + ((v.u >> 16) & 1u);
    return (unsigned short)(r >> 16);
}
__device__ inline float bf2f(unsigned short h) {
    union { unsigned u; float f; } v;
    v.u = ((unsigned)h) << 16;
    return v.f;
}
// truncate fp32 -> bf16-representable fp32 (round-toward-zero), 1 AND
__device__ inline float truncbf(float x) {
    return __uint_as_float(__float_as_uint(x) & 0xFFFF0000u);
}
// pack hi16(a) into low half, hi16(b) into high half — ONE v_perm_b32
__device__ inline unsigned pk2(float a, float b) {
    return __builtin_amdgcn_perm(__float_as_uint(b), __float_as_uint(a), 0x07060302u);
}
__device__ inline v4s pack4trunc(float a, float b, float c, float d) {
    union { unsigned w[2]; v4s s; } u;
    u.w[0] = pk2(a, b);
    u.w[1] = pk2(c, d);
    return u.s;
}
union u64frag { u64 u; v4s s; };

// proj: u16[NP][64][384] row-major bf16, Q-cols pre-scaled by QSCALE.
// Champion structure = R21 (VGPR 64 cliff-edge + T1 XCD swizzle: FETCH
// 27->9.8MB measured). R22: k_route fused into k_tail (each wave redundantly
// computes the block's top-4 from L2-resident qwin/kwin — no extra barrier,
// so the T14 lepe-load hoist stays un-drained) + lsum drops truncbf (bias
// ~0.2% low, absmax headroom 4x).

// ---------------- Kernel 0: pack Wqkv (bf16, QSCALE on Q) + Wo (hi/lo) -----
__global__ __launch_bounds__(256) void k_wprep(const float* __restrict__ Wqkv,
    const float* __restrict__ Wo, u64* __restrict__ wbl,
    u64* __restrict__ wo_hi, u64* __restrict__ wo_lo)
{
    const int e = blockIdx.x * 256 + threadIdx.x;
    if (e < 8 * 24 * 64) {
        const int ks = e / (24 * 64);
        const int jt = (e >> 6) % 24;
        const int lane = e & 63;
        const int lg = lane >> 4, d = lane & 15;
        const int col = jt * 16 + d;
        const int k0 = ks * 16 + lg * 4;
        const float sc = (jt < 8) ? QSCALE : 1.f;
        u64 pk = 0;
        #pragma unroll
        for (int i = 0; i < 4; ++i)
            pk |= ((u64)f2bf(Wqkv[(size_t)(k0 + i) * PROJC + col] * sc)) << (16 * i);
        wbl[e] = pk;
    } else if (e < 8 * 24 * 64 + 8 * 8 * 64) {
        const int e2 = e - 8 * 24 * 64;
        const int ks = e2 >> 9;
        const int jt = (e2 >> 6) & 7;
        const int lane = e2 & 63;
        const int lg = lane >> 4, d = lane & 15;
        const int col = jt * 16 + d;
        const int k0 = ks * 16 + lg * 4;
        u64 ph = 0, pl = 0;
        #pragma unroll
        for (int i = 0; i < 4; ++i) {
            const float v = Wo[(size_t)(k0 + i) * CDIM + col];
            const unsigned short h = f2bf(v);
            const unsigned short l = f2bf(v - bf2f(h));
            ph |= ((u64)h) << (16 * i);
            pl |= ((u64)l) << (16 * i);
        }
        wo_hi[e2] = ph;
        wo_lo[e2] = pl;
    }
}

// ---------------- Kernel 1: QKV projection + fused routing means -----------
__global__ __launch_bounds__(256) void k_qkv(const float* __restrict__ x,
    const u64* __restrict__ wbl, const float* __restrict__ bqkv,
    unsigned short* __restrict__ proj, const float* __restrict__ Wqkv,
    float* __restrict__ qwin, float* __restrict__ kwin)
{
    // T1 XCD swizzle: image n = bid&7 stays on one XCD (x slice L2-resident)
    const int bid = blockIdx.x;
    const int win = (bid & 7) * P2 + (bid >> 3);
    const int ch = blockIdx.y;
    const int n = win / P2, p = win % P2;
    const int wy = p / NWIN, wx = p % NWIN;
    __shared__ __align__(16) float xs[128 * 68];   // [c][t] pad 68 (34.8 KB)
    __shared__ float xm[CDIM];
    const int tid = threadIdx.x;
    const int wq = tid >> 6, lane = tid & 63;
    const int lg = lane >> 4, d = lane & 15;

    #pragma unroll
    for (int s = tid; s < 1024; s += 256) {
        const int c = s >> 3, h8 = s & 7;
        const float* src = x + (size_t)(n * CDIM + c) * 3136 + (wy * 8 + h8) * HH + wx * 8;
        const float4 a = *(const float4*)src;
        const float4 b = *(const float4*)(src + 4);
        *(float4*)&xs[c * 68 + h8 * 8]     = a;
        *(float4*)&xs[c * 68 + h8 * 8 + 4] = b;
    }
    __syncthreads();

    const int m = wq;
    const int jtb = ch * 12;
    f4 acc[12];
    #pragma unroll
    for (int nn = 0; nn < 12; ++nn) {
        const int col = ch * 192 + nn * 16 + d;
        float bb = bqkv[col];
        if (col < 128) bb *= QSCALE;
        acc[nn] = (f4){bb, bb, bb, bb};
    }
    #pragma unroll
    for (int ks = 0; ks < 8; ++ks) {
        u64frag au;
        u64 pk = 0;
        #pragma unroll
        for (int i = 0; i < 4; ++i)
            pk |= ((u64)f2bf(xs[(ks * 16 + lg * 4 + i) * 68 + m * 16 + d])) << (16 * i);
        au.u = pk;
        #pragma unroll
        for (int nn = 0; nn < 12; ++nn) {
            u64frag bu; bu.u = wbl[(size_t)((ks * 24 + jtb + nn) * 64 + lane)];
            acc[nn] = MFMA16(au.s, bu.s, acc[nn]);
        }
    }
    #pragma unroll
    for (int nn = 0; nn < 12; ++nn)
        #pragma unroll
        for (int r = 0; r < 4; ++r)
            proj[(size_t)(win * 64 + m * 16 + lg * 4 + r) * PROJC + ch * 192 + nn * 16 + d]
                = f2bf(acc[nn][r]);

    // ---- fused routing means + fp32 projection (ch==0 blocks only) ----
    if (ch == 0) {
        for (int c = tid; c < CDIM; c += 256) {
            float s = 0.f;
            #pragma unroll 16
            for (int t = 0; t < 64; ++t) s += xs[c * 68 + t];
            xm[c] = s * (1.f / 64.f);
        }
        __syncthreads();
        const int j = tid;      // 0..255
        float s = bqkv[j];
        #pragma unroll 8
        for (int c = 0; c < CDIM; ++c) s = fmaf(xm[c], Wqkv[(size_t)c * PROJC + j], s);
        if (j < 128) qwin[(size_t)win * 128 + j] = s;
        else         kwin[(size_t)win * 128 + j - 128] = s;
    }
}

// ---------------- Kernel 2: fused route + attention + lepe + out GEMM ------
__global__ __launch_bounds__(512) void k_tail(const unsigned short* __restrict__ proj,
    const float* __restrict__ qwin, const float* __restrict__ kwin,
    const u64* __restrict__ wo_hi, const u64* __restrict__ wo_lo,
    const float* __restrict__ lw, const float* __restrict__ lb,
    const float* __restrict__ bo, float* __restrict__ out)
{
    // T1 XCD swizzle: all 49 windows of image n = bid&7 on one XCD -> the
    // image's proj slice (2.4MB) is L2-resident for all gathers below.
    const int bid = blockIdx.x;
    const int win = (bid & 7) * P2 + (bid >> 3);
    const int n = win / P2, p = win % P2;
    const int wy = p / NWIN, wx = p % NWIN;
    __shared__ float o_lds[64 * 132];   // [tok][ch], pad 132 (33.8 KB)
    const int tid = threadIdx.x;
    const int w8 = tid >> 6, lane = tid & 63;
    const int lg = lane >> 4, d = lane & 15;

    // ===== T14 issue-early: lepe tap loads hoisted to kernel top =====
    const int c_l = tid & 127, quad = tid >> 7;
    const int r0 = quad * 2;
    float lw9[9];
    #pragma unroll
    for (int t = 0; t < 9; ++t) lw9[t] = lw[c_l * 9 + t];
    const float bias_l = lb[c_l];
    float val[4][10];
    #pragma unroll
    for (int j = 0; j < 4; ++j) {
        const int gh = min(max(wy * 8 + r0 - 1 + j, 0), HH - 1);
        #pragma unroll
        for (int k = 0; k < 10; ++k) {
            const int gw = min(max(wx * 8 - 1 + k, 0), HH - 1);
            const int pp = (gh >> 3) * NWIN + (gw >> 3);
            const int t2 = (gh & 7) * 8 + (gw & 7);
            val[j][k] = bf2f(proj[((size_t)(n * P2 + pp) * 64 + t2) * PROJC + 256 + c_l]);
        }
    }

    // ===== Fused routing top-4 (per-wave redundant; no extra barrier,
    // so the hoisted loads above stay in flight). qwin/kwin are L2-hot. =====
    int widx[4];
    {
        float v = -INFINITY;
        if (lane < P2) {
            const float* qr = qwin + (size_t)win * 128;
            const float* kr = kwin + ((size_t)n * P2 + lane) * 128;
            float s = 0.f;
            #pragma unroll 8
            for (int c = 0; c < 128; ++c) s = fmaf(qr[c], kr[c], s);
            v = s;
        }
        #pragma unroll
        for (int sel = 0; sel < TOPK; ++sel) {
            float mv = v; int mi = lane;
            #pragma unroll
            for (int off = 32; off >= 1; off >>= 1) {
                const float ov = __shfl_xor(mv, off);
                const int   oi = __shfl_xor(mi, off);
                if (ov > mv || (ov == mv && oi < mi)) { mv = ov; mi = oi; }
            }
            widx[sel] = n * P2 + mi;   // uniform across the wave
            if (lane == mi) v = -INFINITY;
        }
    }

    // ===== Phase 1: attention (wave = head w8, 4 qgroups) =====
    {
        const int h = w8;
        const unsigned short* kvb[4];
        #pragma unroll
        for (int c = 0; c < 4; ++c)
            kvb[c] = proj + (size_t)widx[c] * 64 * PROJC;

        v4s qf[4];
        #pragma unroll
        for (int g = 0; g < 4; ++g)
            qf[g] = *(const v4s*)&proj[((size_t)win * 64 + g * 16 + d) * PROJC + h * 16 + lg * 4];

        f4 oacc[4] = {{0.f,0.f,0.f,0.f},{0.f,0.f,0.f,0.f},{0.f,0.f,0.f,0.f},{0.f,0.f,0.f,0.f}};
        float lsum[4] = {0.f, 0.f, 0.f, 0.f};

        __builtin_amdgcn_s_setprio(1);
        #pragma unroll
        for (int c4 = 0; c4 < 4; ++c4) {
            const unsigned short* base = kvb[c4];
            #pragma unroll
            for (int hf = 0; hf < 2; ++hf) {
                const int k0 = hf * 32;
                v4s vf[2];
                #pragma unroll
                for (int t = 0; t < 2; ++t)
                    #pragma unroll
                    for (int i = 0; i < 4; ++i)
                        vf[t][i] = (short)base[(size_t)(k0 + t * 16 + lg * 4 + i) * PROJC + 256 + h * 16 + d];
                v4s kf[2];
                #pragma unroll
                for (int t = 0; t < 2; ++t)
                    kf[t] = *(const v4s*)&base[(size_t)(k0 + t * 16 + d) * PROJC + 128 + h * 16 + lg * 4];
                #pragma unroll
                for (int t = 0; t < 2; ++t) {
                    #pragma unroll
                    for (int g = 0; g < 4; ++g) {
                        const f4 s = MFMA16(kf[t], qf[g], ((f4){0.f,0.f,0.f,0.f}));
                        const float p0 = exp2f(s.x), p1 = exp2f(s.y);
                        const float p2 = exp2f(s.z), p3 = exp2f(s.w);
                        lsum[g] += (p0 + p1) + (p2 + p3);
                        const v4s pf = pack4trunc(p0, p1, p2, p3);
                        oacc[g] = MFMA16(vf[t], pf, oacc[g]);
                    }
                }
            }
        }
        __builtin_amdgcn_s_setprio(0);
        #pragma unroll
        for (int g = 0; g < 4; ++g) {
            float ls = lsum[g];
            ls += __shfl_xor(ls, 16);
            ls += __shfl_xor(ls, 32);
            const float inv = 1.f / ls;
            f4 o = oacc[g];
            o.x *= inv; o.y *= inv; o.z *= inv; o.w *= inv;
            *(f4*)&o_lds[(g * 16 + d) * 132 + h * 16 + lg * 4] = o;
        }
    }
    __syncthreads();

    // ===== Phase 2: lepe stencil (taps already in registers) =====
    {
        bool vr[4];
        #pragma unroll
        for (int j = 0; j < 4; ++j) {
            const int gh = wy * 8 + r0 - 1 + j;
            vr[j] = (gh >= 0) && (gh < HH);
        }
        bool vc[10];
        #pragma unroll
        for (int k = 0; k < 10; ++k) {
            const int gw = wx * 8 - 1 + k;
            vc[k] = (gw >= 0) && (gw < HH);
        }
        #pragma unroll
        for (int rr = 0; rr < 2; ++rr) {
            const int iy = r0 + rr;
            #pragma unroll
            for (int ix = 0; ix < 8; ++ix) {
                float a = bias_l;
                #pragma unroll
                for (int ky = 0; ky < 3; ++ky)
                    #pragma unroll
                    for (int kx = 0; kx < 3; ++kx) {
                        const float wgt = (vr[rr + ky] && vc[ix + kx]) ? lw9[ky * 3 + kx] : 0.f;
                        a = fmaf(val[rr + ky][ix + kx], wgt, a);
                    }
                o_lds[(iy * 8 + ix) * 132 + c_l] += a;
            }
        }
    }
    __syncthreads();

    // ===== Phase 3: out^T = Wo^T (o+lepe)^T + bo, split-bf16 MFMA =====
    {
        const int jt = w8;     // wave = 16 output channels
        f4 acc[4];
        #pragma unroll
        for (int m = 0; m < 4; ++m) {
            f4 b;
            #pragma unroll
            for (int r = 0; r < 4; ++r) b[r] = bo[jt * 16 + lg * 4 + r];
            acc[m] = b;
        }
        #pragma unroll 2
        for (int ks = 0; ks < 8; ++ks) {
            u64frag ahi, alo;
            ahi.u = wo_hi[(size_t)((ks * 8 + jt) * 64 + lane)];
            alo.u = wo_lo[(size_t)((ks * 8 + jt) * 64 + lane)];
            #pragma unroll
            for (int m = 0; m < 4; ++m) {
                const f4 ov = *(const f4*)&o_lds[(m * 16 + d) * 132 + ks * 16 + lg * 4];
                const v4s bhv = pack4trunc(ov.x, ov.y, ov.z, ov.w);
                const v4s blv = pack4trunc(ov.x - truncbf(ov.x), ov.y - truncbf(ov.y),
                                           ov.z - truncbf(ov.z), ov.w - truncbf(ov.w));
                acc[m] = MFMA16(ahi.s, bhv, acc[m]);
                acc[m] = MFMA16(ahi.s, blv, acc[m]);
                acc[m] = MFMA16(alo.s, bhv, acc[m]);
            }
        }
        #pragma unroll
        for (int m = 0; m < 4; ++m) {
            const int tok = m * 16 + d;
            const int h = wy * 8 + (tok >> 3), w = wx * 8 + (tok & 7);
            #pragma unroll
            for (int r = 0; r < 4; ++r) {
                const int oc = jt * 16 + lg * 4 + r;
                out[((size_t)(n * CDIM + oc)) * 3136 + h * HH + w] = acc[m][r];
            }
        }
    }
}

extern "C" void kernel_launch(void* const* d_in, const int* in_sizes, int n_in,
                              void* d_out, int out_size, void* d_ws, size_t ws_size,
                              hipStream_t stream)
{
    const float* x    = (const float*)d_in[0];
    const float* Wqkv = (const float*)d_in[1];
    const float* bqkv = (const float*)d_in[2];
    const float* lw   = (const float*)d_in[3];
    const float* lb   = (const float*)d_in[4];
    const float* Wo   = (const float*)d_in[5];
    const float* bo   = (const float*)d_in[6];
    float* out = (float*)d_out;

    char* w = (char*)d_ws;
    unsigned short* proj = (unsigned short*)w;  w += (size_t)NP * 64 * PROJC * 2;  // 19.3 MB
    u64*   wbl   = (u64*)w;                     w += (size_t)8 * 24 * 64 * 8;      // 96 KB
    u64*   wo_hi = (u64*)w;                     w += (size_t)8 * 8 * 64 * 8;       // 32 KB
    u64*   wo_lo = (u64*)w;                     w += (size_t)8 * 8 * 64 * 8;       // 32 KB
    float* qwin  = (float*)w;                   w += (size_t)NP * 128 * 4;
    float* kwin  = (float*)w;                   w += (size_t)NP * 128 * 4;

    k_wprep<<<dim3(64), 256, 0, stream>>>(Wqkv, Wo, wbl, wo_hi, wo_lo);
    k_qkv  <<<dim3(NP, 2), 256, 0, stream>>>(x, wbl, bqkv, proj, Wqkv, qwin, kwin);
    k_tail <<<dim3(NP), 512, 0, stream>>>(proj, qwin, kwin, wo_hi, wo_lo, lw, lb, bo, out);
}

// Round 23
// 66.017 us; speedup vs baseline: 1.2281x; 1.2281x over previous
//
#include <hip/hip_runtime.h>
#include <math.h>

#define NWIN 7
#define P2 49
#define NB 8
#define NP 392          // NB*P2
#define CDIM 128
#define HH 56
#define PROJC 384
#define HEADS 8
#define HD 16
#define TOPK 4
#define SCALE 0.08838834764831843f   // 128^-0.5
#define QSCALE 0.12751743050337065f  // SCALE * log2(e); v_exp_f32 computes 2^x

typedef __attribute__((ext_vector_type(4))) float f4;
typedef __attribute__((ext_vector_type(4))) short v4s;
typedef unsigned long long u64;

// gfx950 v_mfma_f32_16x16x16_bf16; fragment maps HW-validated (rounds 5-22):
//   A[row][k]: row=lane&15, k=4*(lane>>4)+i ; B[k][col]: col=lane&15, same k
//   D[row][col]: col=lane&15, row=4*(lane>>4)+reg
#define MFMA16(a,b,c) __builtin_amdgcn_mfma_f32_16x16x16bf16_1k(a,b,c,0,0,0)

__device__ inline unsigned short f2bf(float x) {
    union { float f; unsigned u; } v; v.f = x;
    const unsigned r = v.u + 0x7FFFu + ((v.u >> 16) & 1u);
    return (unsigned short)(r >> 16);
}
__device__ inline float bf2f(unsigned short h) {
    union { unsigned u; float f; } v;
    v.u = ((unsigned)h) << 16;
    return v.f;
}
// truncate fp32 -> bf16-representable fp32 (round-toward-zero), 1 AND
__device__ inline float truncbf(float x) {
    return __uint_as_float(__float_as_uint(x) & 0xFFFF0000u);
}
// pack hi16(a) into low half, hi16(b) into high half — ONE v_perm_b32
__device__ inline unsigned pk2(float a, float b) {
    return __builtin_amdgcn_perm(__float_as_uint(b), __float_as_uint(a), 0x07060302u);
}
__device__ inline v4s pack4trunc(float a, float b, float c, float d) {
    union { unsigned w[2]; v4s s; } u;
    u.w[0] = pk2(a, b);
    u.w[1] = pk2(c, d);
    return u.s;
}
union u64frag { u64 u; v4s s; };

// proj: u16[NP][64][384] row-major bf16, Q-cols pre-scaled by QSCALE.
// Champion = R21 structure. HARD LAW (R20/R22 falsifications): k_tail sits
// exactly at the 64-VGPR occupancy cliff — any phase-1-spanning state growth
// (full K/V hoist, fused route) drops occupancy 28->18% and costs 30+us.
// k_route stays a separate 3us dispatch. R23's only delta vs R21: lsum drops
// truncbf (register-neutral VALU trim; softmax ~0.2% low, 4x headroom).

// ---------------- Kernel 0: pack Wqkv (bf16, QSCALE on Q) + Wo (hi/lo) -----
__global__ __launch_bounds__(256) void k_wprep(const float* __restrict__ Wqkv,
    const float* __restrict__ Wo, u64* __restrict__ wbl,
    u64* __restrict__ wo_hi, u64* __restrict__ wo_lo)
{
    const int e = blockIdx.x * 256 + threadIdx.x;
    if (e < 8 * 24 * 64) {
        const int ks = e / (24 * 64);
        const int jt = (e >> 6) % 24;
        const int lane = e & 63;
        const int lg = lane >> 4, d = lane & 15;
        const int col = jt * 16 + d;
        const int k0 = ks * 16 + lg * 4;
        const float sc = (jt < 8) ? QSCALE : 1.f;
        u64 pk = 0;
        #pragma unroll
        for (int i = 0; i < 4; ++i)
            pk |= ((u64)f2bf(Wqkv[(size_t)(k0 + i) * PROJC + col] * sc)) << (16 * i);
        wbl[e] = pk;
    } else if (e < 8 * 24 * 64 + 8 * 8 * 64) {
        const int e2 = e - 8 * 24 * 64;
        const int ks = e2 >> 9;
        const int jt = (e2 >> 6) & 7;
        const int lane = e2 & 63;
        const int lg = lane >> 4, d = lane & 15;
        const int col = jt * 16 + d;
        const int k0 = ks * 16 + lg * 4;
        u64 ph = 0, pl = 0;
        #pragma unroll
        for (int i = 0; i < 4; ++i) {
            const float v = Wo[(size_t)(k0 + i) * CDIM + col];
            const unsigned short h = f2bf(v);
            const unsigned short l = f2bf(v - bf2f(h));
            ph |= ((u64)h) << (16 * i);
            pl |= ((u64)l) << (16 * i);
        }
        wo_hi[e2] = ph;
        wo_lo[e2] = pl;
    }
}

// ---------------- Kernel 1: QKV projection + fused routing means -----------
__global__ __launch_bounds__(256) void k_qkv(const float* __restrict__ x,
    const u64* __restrict__ wbl, const float* __restrict__ bqkv,
    unsigned short* __restrict__ proj, const float* __restrict__ Wqkv,
    float* __restrict__ qwin, float* __restrict__ kwin)
{
    // T1 XCD swizzle: image n = bid&7 stays on one XCD (x slice L2-resident)
    const int bid = blockIdx.x;
    const int win = (bid & 7) * P2 + (bid >> 3);
    const int ch = blockIdx.y;
    const int n = win / P2, p = win % P2;
    const int wy = p / NWIN, wx = p % NWIN;
    __shared__ __align__(16) float xs[128 * 68];   // [c][t] pad 68 (34.8 KB)
    __shared__ float xm[CDIM];
    const int tid = threadIdx.x;
    const int wq = tid >> 6, lane = tid & 63;
    const int lg = lane >> 4, d = lane & 15;

    #pragma unroll
    for (int s = tid; s < 1024; s += 256) {
        const int c = s >> 3, h8 = s & 7;
        const float* src = x + (size_t)(n * CDIM + c) * 3136 + (wy * 8 + h8) * HH + wx * 8;
        const float4 a = *(const float4*)src;
        const float4 b = *(const float4*)(src + 4);
        *(float4*)&xs[c * 68 + h8 * 8]     = a;
        *(float4*)&xs[c * 68 + h8 * 8 + 4] = b;
    }
    __syncthreads();

    const int m = wq;
    const int jtb = ch * 12;
    f4 acc[12];
    #pragma unroll
    for (int nn = 0; nn < 12; ++nn) {
        const int col = ch * 192 + nn * 16 + d;
        float bb = bqkv[col];
        if (col < 128) bb *= QSCALE;
        acc[nn] = (f4){bb, bb, bb, bb};
    }
    #pragma unroll
    for (int ks = 0; ks < 8; ++ks) {
        u64frag au;
        u64 pk = 0;
        #pragma unroll
        for (int i = 0; i < 4; ++i)
            pk |= ((u64)f2bf(xs[(ks * 16 + lg * 4 + i) * 68 + m * 16 + d])) << (16 * i);
        au.u = pk;
        #pragma unroll
        for (int nn = 0; nn < 12; ++nn) {
            u64frag bu; bu.u = wbl[(size_t)((ks * 24 + jtb + nn) * 64 + lane)];
            acc[nn] = MFMA16(au.s, bu.s, acc[nn]);
        }
    }
    #pragma unroll
    for (int nn = 0; nn < 12; ++nn)
        #pragma unroll
        for (int r = 0; r < 4; ++r)
            proj[(size_t)(win * 64 + m * 16 + lg * 4 + r) * PROJC + ch * 192 + nn * 16 + d]
                = f2bf(acc[nn][r]);

    // ---- fused routing means + fp32 projection (ch==0 blocks only) ----
    if (ch == 0) {
        for (int c = tid; c < CDIM; c += 256) {
            float s = 0.f;
            #pragma unroll 16
            for (int t = 0; t < 64; ++t) s += xs[c * 68 + t];
            xm[c] = s * (1.f / 64.f);
        }
        __syncthreads();
        const int j = tid;      // 0..255
        float s = bqkv[j];
        #pragma unroll 8
        for (int c = 0; c < CDIM; ++c) s = fmaf(xm[c], Wqkv[(size_t)c * PROJC + j], s);
        if (j < 128) qwin[(size_t)win * 128 + j] = s;
        else         kwin[(size_t)win * 128 + j - 128] = s;
    }
}

// ---------------- Kernel B: routing top-4 ----------------
__global__ __launch_bounds__(64) void k_route(const float* __restrict__ qwin,
    const float* __restrict__ kwin, int* __restrict__ ridx)
{
    const int win = blockIdx.x;
    const int n = win / P2;
    const int lane = threadIdx.x;
    float v = -INFINITY;
    if (lane < P2) {
        const float* qr = qwin + (size_t)win * 128;
        const float* kr = kwin + ((size_t)n * P2 + lane) * 128;
        float s = 0.f;
        for (int c = 0; c < 128; ++c) s = fmaf(qr[c], kr[c], s);
        v = s;
    }
    #pragma unroll
    for (int sel = 0; sel < TOPK; ++sel) {
        float mv = v; int mi = lane;
        #pragma unroll
        for (int off = 32; off >= 1; off >>= 1) {
            const float ov = __shfl_xor(mv, off);
            const int   oi = __shfl_xor(mi, off);
            if (ov > mv || (ov == mv && oi < mi)) { mv = ov; mi = oi; }
        }
        if (lane == 0) ridx[win * 4 + sel] = mi;
        if (lane == mi) v = -INFINITY;
    }
}

// ---------------- Kernel 2: fused attention + lepe + output GEMM -----------
__global__ __launch_bounds__(512) void k_tail(const unsigned short* __restrict__ proj,
    const int* __restrict__ ridx, const u64* __restrict__ wo_hi,
    const u64* __restrict__ wo_lo, const float* __restrict__ lw,
    const float* __restrict__ lb, const float* __restrict__ bo,
    float* __restrict__ out)
{
    // T1 XCD swizzle: all 49 windows of image n = bid&7 on one XCD -> the
    // image's proj slice (2.4MB) is L2-resident for all gathers below.
    const int bid = blockIdx.x;
    const int win = (bid & 7) * P2 + (bid >> 3);
    const int n = win / P2, p = win % P2;
    const int wy = p / NWIN, wx = p % NWIN;
    __shared__ float o_lds[64 * 132];   // [tok][ch], pad 132 (33.8 KB)
    const int tid = threadIdx.x;
    const int w8 = tid >> 6, lane = tid & 63;
    const int lg = lane >> 4, d = lane & 15;

    // ===== T14 issue-early: lepe tap loads hoisted to kernel top =====
    const int c_l = tid & 127, quad = tid >> 7;
    const int r0 = quad * 2;
    float lw9[9];
    #pragma unroll
    for (int t = 0; t < 9; ++t) lw9[t] = lw[c_l * 9 + t];
    const float bias_l = lb[c_l];
    float val[4][10];
    #pragma unroll
    for (int j = 0; j < 4; ++j) {
        const int gh = min(max(wy * 8 + r0 - 1 + j, 0), HH - 1);
        #pragma unroll
        for (int k = 0; k < 10; ++k) {
            const int gw = min(max(wx * 8 - 1 + k, 0), HH - 1);
            const int pp = (gh >> 3) * NWIN + (gw >> 3);
            const int t2 = (gh & 7) * 8 + (gw & 7);
            val[j][k] = bf2f(proj[((size_t)(n * P2 + pp) * 64 + t2) * PROJC + 256 + c_l]);
        }
    }

    // ===== Phase 1: attention (wave = head w8, 4 qgroups) =====
    {
        const int h = w8;
        const unsigned short* kvb[4];
        #pragma unroll
        for (int c = 0; c < 4; ++c)
            kvb[c] = proj + (size_t)((n * P2 + ridx[win * 4 + c]) * 64) * PROJC;

        v4s qf[4];
        #pragma unroll
        for (int g = 0; g < 4; ++g)
            qf[g] = *(const v4s*)&proj[((size_t)win * 64 + g * 16 + d) * PROJC + h * 16 + lg * 4];

        f4 oacc[4] = {{0.f,0.f,0.f,0.f},{0.f,0.f,0.f,0.f},{0.f,0.f,0.f,0.f},{0.f,0.f,0.f,0.f}};
        float lsum[4] = {0.f, 0.f, 0.f, 0.f};

        __builtin_amdgcn_s_setprio(1);
        #pragma unroll
        for (int c4 = 0; c4 < 4; ++c4) {
            const unsigned short* base = kvb[c4];
            #pragma unroll
            for (int hf = 0; hf < 2; ++hf) {
                const int k0 = hf * 32;
                v4s vf[2];
                #pragma unroll
                for (int t = 0; t < 2; ++t)
                    #pragma unroll
                    for (int i = 0; i < 4; ++i)
                        vf[t][i] = (short)base[(size_t)(k0 + t * 16 + lg * 4 + i) * PROJC + 256 + h * 16 + d];
                v4s kf[2];
                #pragma unroll
                for (int t = 0; t < 2; ++t)
                    kf[t] = *(const v4s*)&base[(size_t)(k0 + t * 16 + d) * PROJC + 128 + h * 16 + lg * 4];
                #pragma unroll
                for (int t = 0; t < 2; ++t) {
                    #pragma unroll
                    for (int g = 0; g < 4; ++g) {
                        const f4 s = MFMA16(kf[t], qf[g], ((f4){0.f,0.f,0.f,0.f}));
                        const float p0 = exp2f(s.x), p1 = exp2f(s.y);
                        const float p2 = exp2f(s.z), p3 = exp2f(s.w);
                        lsum[g] += (p0 + p1) + (p2 + p3);
                        const v4s pf = pack4trunc(p0, p1, p2, p3);
                        oacc[g] = MFMA16(vf[t], pf, oacc[g]);
                    }
                }
            }
        }
        __builtin_amdgcn_s_setprio(0);
        #pragma unroll
        for (int g = 0; g < 4; ++g) {
            float ls = lsum[g];
            ls += __shfl_xor(ls, 16);
            ls += __shfl_xor(ls, 32);
            const float inv = 1.f / ls;
            f4 o = oacc[g];
            o.x *= inv; o.y *= inv; o.z *= inv; o.w *= inv;
            *(f4*)&o_lds[(g * 16 + d) * 132 + h * 16 + lg * 4] = o;
        }
    }
    __syncthreads();

    // ===== Phase 2: lepe stencil (taps already in registers) =====
    {
        bool vr[4];
        #pragma unroll
        for (int j = 0; j < 4; ++j) {
            const int gh = wy * 8 + r0 - 1 + j;
            vr[j] = (gh >= 0) && (gh < HH);
        }
        bool vc[10];
        #pragma unroll
        for (int k = 0; k < 10; ++k) {
            const int gw = wx * 8 - 1 + k;
            vc[k] = (gw >= 0) && (gw < HH);
        }
        #pragma unroll
        for (int rr = 0; rr < 2; ++rr) {
            const int iy = r0 + rr;
            #pragma unroll
            for (int ix = 0; ix < 8; ++ix) {
                float a = bias_l;
                #pragma unroll
                for (int ky = 0; ky < 3; ++ky)
                    #pragma unroll
                    for (int kx = 0; kx < 3; ++kx) {
                        const float wgt = (vr[rr + ky] && vc[ix + kx]) ? lw9[ky * 3 + kx] : 0.f;
                        a = fmaf(val[rr + ky][ix + kx], wgt, a);
                    }
                o_lds[(iy * 8 + ix) * 132 + c_l] += a;
            }
        }
    }
    __syncthreads();

    // ===== Phase 3: out^T = Wo^T (o+lepe)^T + bo, split-bf16 MFMA =====
    {
        const int jt = w8;     // wave = 16 output channels
        f4 acc[4];
        #pragma unroll
        for (int m = 0; m < 4; ++m) {
            f4 b;
            #pragma unroll
            for (int r = 0; r < 4; ++r) b[r] = bo[jt * 16 + lg * 4 + r];
            acc[m] = b;
        }
        #pragma unroll 2
        for (int ks = 0; ks < 8; ++ks) {
            u64frag ahi, alo;
            ahi.u = wo_hi[(size_t)((ks * 8 + jt) * 64 + lane)];
            alo.u = wo_lo[(size_t)((ks * 8 + jt) * 64 + lane)];
            #pragma unroll
            for (int m = 0; m < 4; ++m) {
                const f4 ov = *(const f4*)&o_lds[(m * 16 + d) * 132 + ks * 16 + lg * 4];
                const v4s bhv = pack4trunc(ov.x, ov.y, ov.z, ov.w);
                const v4s blv = pack4trunc(ov.x - truncbf(ov.x), ov.y - truncbf(ov.y),
                                           ov.z - truncbf(ov.z), ov.w - truncbf(ov.w));
                acc[m] = MFMA16(ahi.s, bhv, acc[m]);
                acc[m] = MFMA16(ahi.s, blv, acc[m]);
                acc[m] = MFMA16(alo.s, bhv, acc[m]);
            }
        }
        #pragma unroll
        for (int m = 0; m < 4; ++m) {
            const int tok = m * 16 + d;
            const int h = wy * 8 + (tok >> 3), w = wx * 8 + (tok & 7);
            #pragma unroll
            for (int r = 0; r < 4; ++r) {
                const int oc = jt * 16 + lg * 4 + r;
                out[((size_t)(n * CDIM + oc)) * 3136 + h * HH + w] = acc[m][r];
            }
        }
    }
}

extern "C" void kernel_launch(void* const* d_in, const int* in_sizes, int n_in,
                              void* d_out, int out_size, void* d_ws, size_t ws_size,
                              hipStream_t stream)
{
    const float* x    = (const float*)d_in[0];
    const float* Wqkv = (const float*)d_in[1];
    const float* bqkv = (const float*)d_in[2];
    const float* lw   = (const float*)d_in[3];
    const float* lb   = (const float*)d_in[4];
    const float* Wo   = (const float*)d_in[5];
    const float* bo   = (const float*)d_in[6];
    float* out = (float*)d_out;

    char* w = (char*)d_ws;
    unsigned short* proj = (unsigned short*)w;  w += (size_t)NP * 64 * PROJC * 2;  // 19.3 MB
    u64*   wbl   = (u64*)w;                     w += (size_t)8 * 24 * 64 * 8;      // 96 KB
    u64*   wo_hi = (u64*)w;                     w += (size_t)8 * 8 * 64 * 8;       // 32 KB
    u64*   wo_lo = (u64*)w;                     w += (size_t)8 * 8 * 64 * 8;       // 32 KB
    float* qwin  = (float*)w;                   w += (size_t)NP * 128 * 4;
    float* kwin  = (float*)w;                   w += (size_t)NP * 128 * 4;
    int*   ridx  = (int*)w;

    k_wprep<<<dim3(64), 256, 0, stream>>>(Wqkv, Wo, wbl, wo_hi, wo_lo);
    k_qkv  <<<dim3(NP, 2), 256, 0, stream>>>(x, wbl, bqkv, proj, Wqkv, qwin, kwin);
    k_route<<<dim3(NP), 64, 0, stream>>>(qwin, kwin, ridx);
    k_tail <<<dim3(NP), 512, 0, stream>>>(proj, ridx, wo_hi, wo_lo, lw, lb, bo, out);
}